// Round 10
// baseline (487.284 us; speedup 1.0000x reference)
//
#include <hip/hip_runtime.h>

#define N_NODES  100000
#define N_EDGES  1600000
#define N_GRAPHS 1024
#define D        128
#define BN_EPS   1e-5f

// --- atomic-free CSR build geometry ---
#define FNSLICE      98                  // ceil(100000/1024) node slices
#define FSLICE_NODES 1024                // nodes per slice (d>>10)
#define FSLICE_CAP   20480               // queue cap: mean 16384, sigma~127
#define QCAP         96                  // per-block LDS bin: mean 41, +12 sigma
#define CCHUNK       4000
#define CGRID        400                 // 400*4000 == N_EDGES

// --- setup_kernel block ranges (256 thr each) ---
#define CVT_BLOCKS   6250                // 100000*128 / (256*8)
#define PW_BLOCKS    384                 // 6*128*128 / 256
#define FOLD_BLOCKS  3                   // 6*128 / 256
#define GST_BLOCKS   5                   // 1025 / 256
#define SETUP_GRID   (CVT_BLOCKS + PW_BLOCKS + FOLD_BLOCKS + GST_BLOCKS + 1)

typedef short bf16x8 __attribute__((ext_vector_type(8)));
typedef float f32x4  __attribute__((ext_vector_type(4)));

__device__ __forceinline__ ushort f2bf(float f) {        // RNE fp32->bf16
    unsigned int b = __float_as_uint(f);
    return (ushort)((b + 0x7fffu + ((b >> 16) & 1u)) >> 16);
}
__device__ __forceinline__ float bflo(unsigned int u) { return __uint_as_float(u << 16); }
__device__ __forceinline__ float bfhi(unsigned int u) { return __uint_as_float(u & 0xffff0000u); }
__device__ __forceinline__ unsigned int packbf(float x, float y) {
    return (unsigned int)f2bf(x) | ((unsigned int)f2bf(y) << 16);
}

// ---------------- setup: cvt_x + prep_w + folds + gstart + misc, one launch ----------------
__global__ __launch_bounds__(256) void setup_kernel(
        const float* __restrict__ x, ushort* __restrict__ xb,
        const float* __restrict__ W1, const float* __restrict__ W2,
        ushort* __restrict__ Wt,
        const float* __restrict__ b1, const float* __restrict__ gamma,
        const float* __restrict__ beta, const float* __restrict__ mean,
        const float* __restrict__ var, const float* __restrict__ b2,
        float* __restrict__ folds,
        const int* __restrict__ batch, int* __restrict__ gstart,
        int* __restrict__ slice_tail, int* __restrict__ offsets) {
    int b = blockIdx.x, t = threadIdx.x;
    if (b < CVT_BLOCKS) {                                  // x -> bf16
        size_t i = ((size_t)b * 256 + t) * 8;
        float4 v0 = *(const float4*)(x + i);
        float4 v1 = *(const float4*)(x + i + 4);
        uint4 o;
        o.x = packbf(v0.x, v0.y); o.y = packbf(v0.z, v0.w);
        o.z = packbf(v1.x, v1.y); o.w = packbf(v1.z, v1.w);
        *(uint4*)(xb + i) = o;
    } else if (b < CVT_BLOCKS + PW_BLOCKS) {               // W -> bf16 transposed
        int idx = (b - CVT_BLOCKS) * 256 + t;              // [0, 6*16384)
        int i = idx >> 14, r = idx & 16383;
        int n = r >> 7, k = r & 127, l = i >> 1;
        const float* W = (i & 1) ? (W2 + (size_t)l * D * D) : (W1 + (size_t)l * D * D);
        Wt[idx] = f2bf(W[k * D + n]);
    } else if (b < CVT_BLOCKS + PW_BLOCKS + FOLD_BLOCKS) { // BN folds
        int idx = (b - CVT_BLOCKS - PW_BLOCKS) * 256 + t;  // [0, 768)
        if (idx < 6 * D) {
            int i = idx >> 7, j = idx & 127, l = i >> 1;
            float s, o;
            if ((i & 1) == 0) {
                float sv = gamma[l * D + j] * rsqrtf(var[l * D + j] + BN_EPS);
                s = sv;
                o = (b1[l * D + j] - mean[l * D + j]) * sv + beta[l * D + j];
            } else {
                s = 1.0f;
                o = b2[l * D + j];
            }
            folds[(size_t)i * 2 * D + j]     = s;
            folds[(size_t)i * 2 * D + D + j] = o;
        }
    } else if (b < CVT_BLOCKS + PW_BLOCKS + FOLD_BLOCKS + GST_BLOCKS) {  // gstart
        int g = (b - CVT_BLOCKS - PW_BLOCKS - FOLD_BLOCKS) * 256 + t;
        if (g <= N_GRAPHS) {
            int lo = 0, hi = N_NODES;
            while (lo < hi) {
                int mid = (lo + hi) >> 1;
                if (batch[mid] < g) lo = mid + 1; else hi = mid;
            }
            gstart[g] = lo;
        }
    } else {                                               // misc
        if (t < FNSLICE) slice_tail[t] = 0;
        if (t == 255) offsets[N_NODES] = N_EDGES;
    }
}

// ---------------- CSR pass 1: bin edges by 1024-node slice (LDS), bulk-append ----------------
__global__ __launch_bounds__(256) void compact_kernel(const int* __restrict__ src,
                                                      const int* __restrict__ dst,
                                                      unsigned int* __restrict__ squeue,
                                                      int* __restrict__ slice_tail) {
    __shared__ unsigned int qbuf[FNSLICE * QCAP];   // 37.6 KB
    __shared__ int qcnt[FNSLICE];
    __shared__ int qbase[FNSLICE];
    int t = threadIdx.x;
    for (int i = t; i < FNSLICE; i += 256) qcnt[i] = 0;
    __syncthreads();
    int e0 = blockIdx.x * CCHUNK;
    int eend = e0 + CCHUNK; if (eend > N_EDGES) eend = N_EDGES;
    for (int e = e0 + t; e < eend; e += 256) {
        int d = dst[e], s = src[e];
        int sl = d >> 10;
        unsigned int pk = ((unsigned int)(d & 1023) << 17) | (unsigned int)s;
        int pos = atomicAdd(&qcnt[sl], 1);
        if (pos < QCAP) qbuf[sl * QCAP + pos] = pk;
        else {  // ~never (12-sigma): direct spill, still correct
            int gp = atomicAdd(&slice_tail[sl], 1);
            squeue[(size_t)sl * FSLICE_CAP + gp] = pk;
        }
    }
    __syncthreads();
    for (int i = t; i < FNSLICE; i += 256) {
        int n = qcnt[i]; if (n > QCAP) n = QCAP;
        qbase[i] = atomicAdd(&slice_tail[i], n);
    }
    __syncthreads();
    int wv = t >> 6, ln = t & 63;
    for (int sl = wv; sl < FNSLICE; sl += 4) {
        int n = qcnt[sl]; if (n > QCAP) n = QCAP;
        int gb = qbase[sl];
        for (int i = ln; i < n; i += 64)
            squeue[(size_t)sl * FSLICE_CAP + gb + i] = qbuf[sl * QCAP + i];
    }
}

// ---------------- CSR pass 2: per-slice hist -> scan -> fill, LDS atomics only ----------------
// Absorbs the old slice_scan (each block redundantly scans the 98 slice totals)
// and uses a wave-shuffle scan (2 barriers) instead of 20-barrier Hillis-Steele.
__global__ __launch_bounds__(1024) void fill_local(const unsigned int* __restrict__ squeue,
                                                   const int* __restrict__ slice_tail,
                                                   int* __restrict__ offsets,
                                                   int* __restrict__ csr_src) {
    __shared__ int hist[FSLICE_NODES];
    __shared__ int cur[FSLICE_NODES];
    __shared__ int sbase[128];
    __shared__ int wsum[16];
    int sl = blockIdx.x, t = threadIdx.x;
    int n = slice_tail[sl];
    if (t < 128) sbase[t] = (t < FNSLICE) ? slice_tail[t] : 0;
    hist[t] = 0;
    __syncthreads();
    for (int off = 1; off < 128; off <<= 1) {      // in-block scan of slice totals
        int u = (t < 128 && t >= off) ? sbase[t - off] : 0;
        __syncthreads();
        if (t < 128) sbase[t] += u;
        __syncthreads();
    }
    int gbase = (sl == 0) ? 0 : sbase[sl - 1];
    size_t qb = (size_t)sl * FSLICE_CAP;
    for (int i = t; i < n; i += 1024)
        atomicAdd(&hist[squeue[qb + i] >> 17], 1);
    __syncthreads();
    int c = hist[t];
    int lane = t & 63, w = t >> 6;
    int sc = c;
#pragma unroll
    for (int off = 1; off < 64; off <<= 1) {       // wave-inclusive scan
        int u = __shfl_up(sc, off, 64);
        if (lane >= off) sc += u;
    }
    if (lane == 63) wsum[w] = sc;
    __syncthreads();
    if (t < 16) {                                  // scan the 16 wave sums
        int ws = wsum[t];
        int s2 = ws;
#pragma unroll
        for (int off = 1; off < 16; off <<= 1) {
            int u = __shfl_up(s2, off, 16);
            if (t >= off) s2 += u;
        }
        wsum[t] = s2 - ws;                         // exclusive wave prefix
    }
    __syncthreads();
    int gslot = gbase + sc + wsum[w] - c;          // global exclusive slot
    cur[t] = gslot;
    int node = sl * FSLICE_NODES + t;
    if (node < N_NODES) offsets[node] = gslot;
    __syncthreads();
    for (int i = t; i < n; i += 1024) {
        unsigned int p = squeue[qb + i];
        int slot = atomicAdd(&cur[p >> 17], 1);    // LDS atomic
        csr_src[slot] = (int)(p & 0x1FFFFu);
    }
}

// ---------------- aggregation (bf16 rows, fp32 accumulate, 16 outstanding) ----------------
// 1024-thread blocks (16 nodes each): fewer CP scheduling events than 25000
// 256-thr blocks; 32 VGPR -> full 8 waves/SIMD residency.
__global__ __launch_bounds__(1024) void gather_bf16(const ushort* __restrict__ xb,
                                                    const int* __restrict__ offsets,
                                                    const int* __restrict__ csr_src,
                                                    ushort* __restrict__ hb) {
    int wv = threadIdx.x >> 6, lane = threadIdx.x & 63;
    int node = blockIdx.x * 16 + wv;          // 6250*16 == N_NODES
    const unsigned int* base = (const unsigned int*)xb;
    unsigned int u = base[(size_t)node * 64 + lane];
    float ax = bflo(u), ay = bfhi(u);
    int b = offsets[node], e = offsets[node + 1];
    int i = b;
    for (; i + 15 < e; i += 16) {             // 16 outstanding row loads
        int s0 = csr_src[i],      s1 = csr_src[i + 1],  s2 = csr_src[i + 2],  s3 = csr_src[i + 3];
        int s4 = csr_src[i + 4],  s5 = csr_src[i + 5],  s6 = csr_src[i + 6],  s7 = csr_src[i + 7];
        int s8 = csr_src[i + 8],  s9 = csr_src[i + 9],  sa = csr_src[i + 10], sb = csr_src[i + 11];
        int sc = csr_src[i + 12], sd = csr_src[i + 13], se = csr_src[i + 14], sf = csr_src[i + 15];
        unsigned int v0 = base[(size_t)s0 * 64 + lane];
        unsigned int v1 = base[(size_t)s1 * 64 + lane];
        unsigned int v2 = base[(size_t)s2 * 64 + lane];
        unsigned int v3 = base[(size_t)s3 * 64 + lane];
        unsigned int v4 = base[(size_t)s4 * 64 + lane];
        unsigned int v5 = base[(size_t)s5 * 64 + lane];
        unsigned int v6 = base[(size_t)s6 * 64 + lane];
        unsigned int v7 = base[(size_t)s7 * 64 + lane];
        unsigned int v8 = base[(size_t)s8 * 64 + lane];
        unsigned int v9 = base[(size_t)s9 * 64 + lane];
        unsigned int va = base[(size_t)sa * 64 + lane];
        unsigned int vb = base[(size_t)sb * 64 + lane];
        unsigned int vc = base[(size_t)sc * 64 + lane];
        unsigned int vd = base[(size_t)sd * 64 + lane];
        unsigned int ve = base[(size_t)se * 64 + lane];
        unsigned int vf = base[(size_t)sf * 64 + lane];
        ax += bflo(v0) + bflo(v1) + bflo(v2) + bflo(v3)
            + bflo(v4) + bflo(v5) + bflo(v6) + bflo(v7)
            + bflo(v8) + bflo(v9) + bflo(va) + bflo(vb)
            + bflo(vc) + bflo(vd) + bflo(ve) + bflo(vf);
        ay += bfhi(v0) + bfhi(v1) + bfhi(v2) + bfhi(v3)
            + bfhi(v4) + bfhi(v5) + bfhi(v6) + bfhi(v7)
            + bfhi(v8) + bfhi(v9) + bfhi(va) + bfhi(vb)
            + bfhi(vc) + bfhi(vd) + bfhi(ve) + bfhi(vf);
    }
    for (; i + 3 < e; i += 4) {
        int s0 = csr_src[i], s1 = csr_src[i + 1], s2 = csr_src[i + 2], s3 = csr_src[i + 3];
        unsigned int v0 = base[(size_t)s0 * 64 + lane];
        unsigned int v1 = base[(size_t)s1 * 64 + lane];
        unsigned int v2 = base[(size_t)s2 * 64 + lane];
        unsigned int v3 = base[(size_t)s3 * 64 + lane];
        ax += bflo(v0) + bflo(v1) + bflo(v2) + bflo(v3);
        ay += bfhi(v0) + bfhi(v1) + bfhi(v2) + bfhi(v3);
    }
    for (; i < e; ++i) {
        unsigned int v = base[(size_t)csr_src[i] * 64 + lane];
        ax += bflo(v); ay += bfhi(v);
    }
    ((unsigned int*)hb)[(size_t)node * 64 + lane] = packbf(ax, ay);
}

// ---------------- fused layer: out = relu(relu(BN(in@W1))@W2 + b2) ----------------
// R9 structure (proven): 512 thr, 128x128 tile, one Bs time-multiplexed W1->W2,
// As aliased A->H->C (wave-private rows). 68 KB LDS -> 2 blocks/CU.
__global__ __launch_bounds__(512, 4) void fused_gemm(const ushort* __restrict__ in,
                                                     ushort* __restrict__ out,
                                                     const ushort* __restrict__ Wt1,
                                                     const ushort* __restrict__ Wt2,
                                                     const float* __restrict__ fold1,
                                                     const float* __restrict__ fold2) {
    __shared__ ushort As[128 * 136];    // A tile -> H tile -> C tile (aliased)
    __shared__ ushort Bs[128 * 136];    // W1^T, then W2^T
    int t = threadIdx.x;
    int row0 = blockIdx.x * 128;        // 782 blocks, last partial (32 rows)

#pragma unroll
    for (int i = 0; i < 4; ++i) {       // stage A + W1
        int f = t + 512 * i; int m = f >> 4, g = f & 15;
        *(float4*)(As + m * 136 + g * 8) = *(const float4*)(in + (size_t)(row0 + m) * D + g * 8);
        *(float4*)(Bs + m * 136 + g * 8) = *(const float4*)(Wt1 + (size_t)m * D + g * 8);
    }
    __syncthreads();

    int lane = t & 63, wv = t >> 6;
    int quad = lane >> 4, mr = lane & 15;
    int mbase = wv * 16;
    const ushort* ap = As + (mbase + mr) * 136 + quad * 8;
    bf16x8 a0 = *(const bf16x8*)(ap);
    bf16x8 a1 = *(const bf16x8*)(ap + 32);
    bf16x8 a2 = *(const bf16x8*)(ap + 64);
    bf16x8 a3 = *(const bf16x8*)(ap + 96);

    // --- GEMM1: H = relu(BN(A@W1)) -> As own rows (in-wave DS ordering: safe)
#pragma unroll
    for (int nt = 0; nt < 8; ++nt) {
        const ushort* bq = Bs + (nt * 16 + mr) * 136 + quad * 8;
        bf16x8 b0 = *(const bf16x8*)(bq);
        bf16x8 b1 = *(const bf16x8*)(bq + 32);
        bf16x8 b2 = *(const bf16x8*)(bq + 64);
        bf16x8 b3 = *(const bf16x8*)(bq + 96);
        f32x4 acc = {0.f, 0.f, 0.f, 0.f};
        acc = __builtin_amdgcn_mfma_f32_16x16x32_bf16(a0, b0, acc, 0, 0, 0);
        acc = __builtin_amdgcn_mfma_f32_16x16x32_bf16(a1, b1, acc, 0, 0, 0);
        acc = __builtin_amdgcn_mfma_f32_16x16x32_bf16(a2, b2, acc, 0, 0, 0);
        acc = __builtin_amdgcn_mfma_f32_16x16x32_bf16(a3, b3, acc, 0, 0, 0);
        int j = nt * 16 + mr;           // C/D: col=lane&15, row=quad*4+reg (m89)
        float s = fold1[j], o = fold1[D + j];
#pragma unroll
        for (int r = 0; r < 4; ++r) {
            float z = fmaxf(fmaf(acc[r], s, o), 0.0f);
            As[(mbase + quad * 4 + r) * 136 + j] = f2bf(z);
        }
    }
    __syncthreads();                    // all waves done reading W1 from Bs

#pragma unroll
    for (int i = 0; i < 4; ++i) {       // re-stage Bs with W2
        int f = t + 512 * i; int m = f >> 4, g = f & 15;
        *(float4*)(Bs + m * 136 + g * 8) = *(const float4*)(Wt2 + (size_t)m * D + g * 8);
    }
    const ushort* hp = As + (mbase + mr) * 136 + quad * 8;
    bf16x8 h0 = *(const bf16x8*)(hp);
    bf16x8 h1 = *(const bf16x8*)(hp + 32);
    bf16x8 h2 = *(const bf16x8*)(hp + 64);
    bf16x8 h3 = *(const bf16x8*)(hp + 96);
    __syncthreads();                    // W2 staged

    // --- GEMM2: C = relu(H@W2 + b2) -> As own rows
#pragma unroll
    for (int nt = 0; nt < 8; ++nt) {
        const ushort* bq = Bs + (nt * 16 + mr) * 136 + quad * 8;
        bf16x8 b0 = *(const bf16x8*)(bq);
        bf16x8 b1 = *(const bf16x8*)(bq + 32);
        bf16x8 b2 = *(const bf16x8*)(bq + 64);
        bf16x8 b3 = *(const bf16x8*)(bq + 96);
        f32x4 acc = {0.f, 0.f, 0.f, 0.f};
        acc = __builtin_amdgcn_mfma_f32_16x16x32_bf16(h0, b0, acc, 0, 0, 0);
        acc = __builtin_amdgcn_mfma_f32_16x16x32_bf16(h1, b1, acc, 0, 0, 0);
        acc = __builtin_amdgcn_mfma_f32_16x16x32_bf16(h2, b2, acc, 0, 0, 0);
        acc = __builtin_amdgcn_mfma_f32_16x16x32_bf16(h3, b3, acc, 0, 0, 0);
        int j = nt * 16 + mr;
        float o = fold2[D + j];
#pragma unroll
        for (int r = 0; r < 4; ++r) {
            float z = fmaxf(acc[r] + o, 0.0f);
            As[(mbase + quad * 4 + r) * 136 + j] = f2bf(z);
        }
    }
    __syncthreads();

#pragma unroll
    for (int i = 0; i < 8; ++i) {       // coalesced copy-out, float2 = 4 bf16
        int f = t + 512 * i; int lr = f >> 5, g = f & 31;
        if (row0 + lr < N_NODES)
            *(float2*)(out + (size_t)(row0 + lr) * D + g * 4) =
                *(const float2*)(As + lr * 136 + g * 4);
    }
}

// ---------------- pooling + head fused: out[r] = relu(pool(r)@W1+b1)@W2+b2 ----------------
__global__ __launch_bounds__(128) void poolhead_kernel(const ushort* __restrict__ xb,
                                                       const int* __restrict__ gstart,
                                                       const float* __restrict__ W1,
                                                       const float* __restrict__ b1,
                                                       const float* __restrict__ W2,
                                                       const float* __restrict__ b2,
                                                       float* __restrict__ out) {
    __shared__ float row[128];
    __shared__ float t1[128];
    int r = blockIdx.x, j = threadIdx.x;
    float acc = 0.0f;
    int b = gstart[r], e = gstart[r + 1];
    for (int i = b; i < e; ++i)
        acc += __uint_as_float(((unsigned int)xb[(size_t)i * D + j]) << 16);
    row[j] = acc;
    __syncthreads();
    float a1 = b1[j];
    for (int k = 0; k < D; ++k) a1 = fmaf(row[k], W1[k * D + j], a1);
    t1[j] = fmaxf(a1, 0.0f);
    __syncthreads();
    float a2 = b2[j];
    for (int k = 0; k < D; ++k) a2 = fmaf(t1[k], W2[k * D + j], a2);
    out[r * D + j] = a2;
}

// ---------------- launcher ----------------
extern "C" void kernel_launch(void* const* d_in, const int* in_sizes, int n_in,
                              void* d_out, int out_size, void* d_ws, size_t ws_size,
                              hipStream_t stream) {
    const float* x        = (const float*)d_in[0];
    const int*   ei       = (const int*)d_in[1];
    const int*   src      = ei;
    const int*   dst      = ei + N_EDGES;
    const int*   batch    = (const int*)d_in[2];
    const float* conv_W1  = (const float*)d_in[3];
    const float* conv_b1  = (const float*)d_in[4];
    const float* bn_gamma = (const float*)d_in[5];
    const float* bn_beta  = (const float*)d_in[6];
    const float* bn_mean  = (const float*)d_in[7];
    const float* bn_var   = (const float*)d_in[8];
    const float* conv_W2  = (const float*)d_in[9];
    const float* conv_b2  = (const float*)d_in[10];
    const float* head_W1  = (const float*)d_in[11];
    const float* head_b1  = (const float*)d_in[12];
    const float* head_W2  = (const float*)d_in[13];
    const float* head_b2  = (const float*)d_in[14];
    float* out = (float*)d_out;

    char* ws = (char*)d_ws;
    size_t off = 0;
    auto alloc = [&](size_t bytes) -> void* {
        void* p = ws + off;
        off = (off + bytes + 255) & ~(size_t)255;
        return p;
    };
    const size_t NODE_BUF = (size_t)(N_NODES + 128) * D * sizeof(ushort);
    ushort* buf0    = (ushort*)alloc(NODE_BUF);
    ushort* buf1    = (ushort*)alloc(NODE_BUF);
    ushort* Wt      = (ushort*)alloc((size_t)6 * D * D * sizeof(ushort));
    float*  folds   = (float*)alloc((size_t)6 * 2 * D * sizeof(float));
    unsigned int* squeue = (unsigned int*)alloc((size_t)FNSLICE * FSLICE_CAP * sizeof(unsigned int));
    int*   csr_src  = (int*)alloc((size_t)N_EDGES * sizeof(int));
    int*   offsets  = (int*)alloc((size_t)(N_NODES + 1) * sizeof(int));
    int*   slice_tail = (int*)alloc((size_t)FNSLICE * sizeof(int));
    int*   gstart   = (int*)alloc((size_t)(N_GRAPHS + 1) * sizeof(int));

    setup_kernel<<<SETUP_GRID, 256, 0, stream>>>(
        x, buf0, conv_W1, conv_W2, Wt,
        conv_b1, bn_gamma, bn_beta, bn_mean, bn_var, conv_b2, folds,
        batch, gstart, slice_tail, offsets);
    compact_kernel<<<CGRID, 256, 0, stream>>>(src, dst, squeue, slice_tail);
    fill_local<<<FNSLICE, 1024, 0, stream>>>(squeue, slice_tail, offsets, csr_src);

    const int FUSED_GRID = (N_NODES + 127) / 128;   // 782
    for (int l = 0; l < 3; ++l) {
        gather_bf16<<<N_NODES / 16, 1024, 0, stream>>>(buf0, offsets, csr_src, buf1);
        fused_gemm<<<FUSED_GRID, 512, 0, stream>>>(buf1, buf0,
            Wt + (size_t)(2 * l) * D * D, Wt + (size_t)(2 * l + 1) * D * D,
            folds + (size_t)(2 * l) * 2 * D, folds + (size_t)(2 * l + 1) * 2 * D);
    }

    poolhead_kernel<<<N_GRAPHS, 128, 0, stream>>>(buf0, gstart, head_W1, head_b1,
                                                  head_W2, head_b2, out);
}

// Round 11
// 447.000 us; speedup vs baseline: 1.0901x; 1.0901x over previous
//
#include <hip/hip_runtime.h>

#define N_NODES  100000
#define N_EDGES  1600000
#define N_GRAPHS 1024
#define D        128
#define BN_EPS   1e-5f

// --- atomic-free CSR build geometry ---
#define FNSLICE      98                  // ceil(100000/1024) node slices
#define FSLICE_NODES 1024                // nodes per slice (d>>10)
#define FSLICE_CAP   20480               // queue cap: mean 16384, sigma~127
#define QCAP         96                  // per-block LDS bin: mean 41, +12 sigma
#define CCHUNK       4000
#define CGRID        400                 // 400*4000 == N_EDGES

// --- setup_kernel block ranges (256 thr each) ---
#define CVT_BLOCKS   6250                // 100000*128 / (256*8)
#define PW_BLOCKS    384                 // 6*128*128 / 256
#define FOLD_BLOCKS  3                   // 6*128 / 256
#define GST_BLOCKS   5                   // 1025 / 256
#define SETUP_GRID   (CVT_BLOCKS + PW_BLOCKS + FOLD_BLOCKS + GST_BLOCKS + 1)

typedef short bf16x8 __attribute__((ext_vector_type(8)));
typedef float f32x4  __attribute__((ext_vector_type(4)));

__device__ __forceinline__ ushort f2bf(float f) {        // RNE fp32->bf16
    unsigned int b = __float_as_uint(f);
    return (ushort)((b + 0x7fffu + ((b >> 16) & 1u)) >> 16);
}
__device__ __forceinline__ float bflo(unsigned int u) { return __uint_as_float(u << 16); }
__device__ __forceinline__ float bfhi(unsigned int u) { return __uint_as_float(u & 0xffff0000u); }
__device__ __forceinline__ unsigned int packbf(float x, float y) {
    return (unsigned int)f2bf(x) | ((unsigned int)f2bf(y) << 16);
}

// ---------------- setup: cvt_x + prep_w + folds + gstart + misc, one launch ----------------
__global__ __launch_bounds__(256) void setup_kernel(
        const float* __restrict__ x, ushort* __restrict__ xb,
        const float* __restrict__ W1, const float* __restrict__ W2,
        ushort* __restrict__ Wt,
        const float* __restrict__ b1, const float* __restrict__ gamma,
        const float* __restrict__ beta, const float* __restrict__ mean,
        const float* __restrict__ var, const float* __restrict__ b2,
        float* __restrict__ folds,
        const int* __restrict__ batch, int* __restrict__ gstart,
        int* __restrict__ slice_tail, int* __restrict__ offsets) {
    int b = blockIdx.x, t = threadIdx.x;
    if (b < CVT_BLOCKS) {                                  // x -> bf16
        size_t i = ((size_t)b * 256 + t) * 8;
        float4 v0 = *(const float4*)(x + i);
        float4 v1 = *(const float4*)(x + i + 4);
        uint4 o;
        o.x = packbf(v0.x, v0.y); o.y = packbf(v0.z, v0.w);
        o.z = packbf(v1.x, v1.y); o.w = packbf(v1.z, v1.w);
        *(uint4*)(xb + i) = o;
    } else if (b < CVT_BLOCKS + PW_BLOCKS) {               // W -> bf16 transposed
        int idx = (b - CVT_BLOCKS) * 256 + t;              // [0, 6*16384)
        int i = idx >> 14, r = idx & 16383;
        int n = r >> 7, k = r & 127, l = i >> 1;
        const float* W = (i & 1) ? (W2 + (size_t)l * D * D) : (W1 + (size_t)l * D * D);
        Wt[idx] = f2bf(W[k * D + n]);
    } else if (b < CVT_BLOCKS + PW_BLOCKS + FOLD_BLOCKS) { // BN folds
        int idx = (b - CVT_BLOCKS - PW_BLOCKS) * 256 + t;  // [0, 768)
        if (idx < 6 * D) {
            int i = idx >> 7, j = idx & 127, l = i >> 1;
            float s, o;
            if ((i & 1) == 0) {
                float sv = gamma[l * D + j] * rsqrtf(var[l * D + j] + BN_EPS);
                s = sv;
                o = (b1[l * D + j] - mean[l * D + j]) * sv + beta[l * D + j];
            } else {
                s = 1.0f;
                o = b2[l * D + j];
            }
            folds[(size_t)i * 2 * D + j]     = s;
            folds[(size_t)i * 2 * D + D + j] = o;
        }
    } else if (b < CVT_BLOCKS + PW_BLOCKS + FOLD_BLOCKS + GST_BLOCKS) {  // gstart
        int g = (b - CVT_BLOCKS - PW_BLOCKS - FOLD_BLOCKS) * 256 + t;
        if (g <= N_GRAPHS) {
            int lo = 0, hi = N_NODES;
            while (lo < hi) {
                int mid = (lo + hi) >> 1;
                if (batch[mid] < g) lo = mid + 1; else hi = mid;
            }
            gstart[g] = lo;
        }
    } else {                                               // misc
        if (t < FNSLICE) slice_tail[t] = 0;
        if (t == 255) offsets[N_NODES] = N_EDGES;
    }
}

// ---------------- CSR pass 1: bin edges by 1024-node slice (LDS), bulk-append ----------------
__global__ __launch_bounds__(256) void compact_kernel(const int* __restrict__ src,
                                                      const int* __restrict__ dst,
                                                      unsigned int* __restrict__ squeue,
                                                      int* __restrict__ slice_tail) {
    __shared__ unsigned int qbuf[FNSLICE * QCAP];   // 37.6 KB
    __shared__ int qcnt[FNSLICE];
    __shared__ int qbase[FNSLICE];
    int t = threadIdx.x;
    for (int i = t; i < FNSLICE; i += 256) qcnt[i] = 0;
    __syncthreads();
    int e0 = blockIdx.x * CCHUNK;
    int eend = e0 + CCHUNK; if (eend > N_EDGES) eend = N_EDGES;
    for (int e = e0 + t; e < eend; e += 256) {
        int d = dst[e], s = src[e];
        int sl = d >> 10;
        unsigned int pk = ((unsigned int)(d & 1023) << 17) | (unsigned int)s;
        int pos = atomicAdd(&qcnt[sl], 1);
        if (pos < QCAP) qbuf[sl * QCAP + pos] = pk;
        else {  // ~never (12-sigma): direct spill, still correct
            int gp = atomicAdd(&slice_tail[sl], 1);
            squeue[(size_t)sl * FSLICE_CAP + gp] = pk;
        }
    }
    __syncthreads();
    for (int i = t; i < FNSLICE; i += 256) {
        int n = qcnt[i]; if (n > QCAP) n = QCAP;
        qbase[i] = atomicAdd(&slice_tail[i], n);
    }
    __syncthreads();
    int wv = t >> 6, ln = t & 63;
    for (int sl = wv; sl < FNSLICE; sl += 4) {
        int n = qcnt[sl]; if (n > QCAP) n = QCAP;
        int gb = qbase[sl];
        for (int i = ln; i < n; i += 64)
            squeue[(size_t)sl * FSLICE_CAP + gb + i] = qbuf[sl * QCAP + i];
    }
}

// ---------------- CSR pass 2: per-slice hist -> scan -> fill, LDS atomics only ----------------
__global__ __launch_bounds__(1024) void fill_local(const unsigned int* __restrict__ squeue,
                                                   const int* __restrict__ slice_tail,
                                                   int* __restrict__ offsets,
                                                   int* __restrict__ csr_src) {
    __shared__ int hist[FSLICE_NODES];
    __shared__ int cur[FSLICE_NODES];
    __shared__ int sbase[128];
    __shared__ int wsum[16];
    int sl = blockIdx.x, t = threadIdx.x;
    int n = slice_tail[sl];
    if (t < 128) sbase[t] = (t < FNSLICE) ? slice_tail[t] : 0;
    hist[t] = 0;
    __syncthreads();
    for (int off = 1; off < 128; off <<= 1) {      // in-block scan of slice totals
        int u = (t < 128 && t >= off) ? sbase[t - off] : 0;
        __syncthreads();
        if (t < 128) sbase[t] += u;
        __syncthreads();
    }
    int gbase = (sl == 0) ? 0 : sbase[sl - 1];
    size_t qb = (size_t)sl * FSLICE_CAP;
    for (int i = t; i < n; i += 1024)
        atomicAdd(&hist[squeue[qb + i] >> 17], 1);
    __syncthreads();
    int c = hist[t];
    int lane = t & 63, w = t >> 6;
    int sc = c;
#pragma unroll
    for (int off = 1; off < 64; off <<= 1) {       // wave-inclusive scan
        int u = __shfl_up(sc, off, 64);
        if (lane >= off) sc += u;
    }
    if (lane == 63) wsum[w] = sc;
    __syncthreads();
    if (t < 16) {                                  // scan the 16 wave sums
        int ws = wsum[t];
        int s2 = ws;
#pragma unroll
        for (int off = 1; off < 16; off <<= 1) {
            int u = __shfl_up(s2, off, 16);
            if (t >= off) s2 += u;
        }
        wsum[t] = s2 - ws;                         // exclusive wave prefix
    }
    __syncthreads();
    int gslot = gbase + sc + wsum[w] - c;          // global exclusive slot
    cur[t] = gslot;
    int node = sl * FSLICE_NODES + t;
    if (node < N_NODES) offsets[node] = gslot;
    __syncthreads();
    for (int i = t; i < n; i += 1024) {
        unsigned int p = squeue[qb + i];
        int slot = atomicAdd(&cur[p >> 17], 1);    // LDS atomic
        csr_src[slot] = (int)(p & 0x1FFFFu);
    }
}

// ---------------- aggregation (bf16 rows, fp32 accumulate, 16 outstanding) ----------------
// R9 shape restored: 256 thr / 4 nodes per block. R10 lesson: 1024-thr blocks
// couple 16 variable-degree nodes into one retirement unit -> occupancy 68->49%
// and +16 us/dispatch. Fine-grained blocks let the CU backfill continuously.
__global__ __launch_bounds__(256) void gather_bf16(const ushort* __restrict__ xb,
                                                   const int* __restrict__ offsets,
                                                   const int* __restrict__ csr_src,
                                                   ushort* __restrict__ hb) {
    int wv = threadIdx.x >> 6, lane = threadIdx.x & 63;
    int node = blockIdx.x * 4 + wv;           // 25000*4 == N_NODES
    const unsigned int* base = (const unsigned int*)xb;
    unsigned int u = base[(size_t)node * 64 + lane];
    float ax = bflo(u), ay = bfhi(u);
    int b = offsets[node], e = offsets[node + 1];
    int i = b;
    for (; i + 15 < e; i += 16) {             // 16 outstanding row loads
        int s0 = csr_src[i],      s1 = csr_src[i + 1],  s2 = csr_src[i + 2],  s3 = csr_src[i + 3];
        int s4 = csr_src[i + 4],  s5 = csr_src[i + 5],  s6 = csr_src[i + 6],  s7 = csr_src[i + 7];
        int s8 = csr_src[i + 8],  s9 = csr_src[i + 9],  sa = csr_src[i + 10], sb = csr_src[i + 11];
        int sc = csr_src[i + 12], sd = csr_src[i + 13], se = csr_src[i + 14], sf = csr_src[i + 15];
        unsigned int v0 = base[(size_t)s0 * 64 + lane];
        unsigned int v1 = base[(size_t)s1 * 64 + lane];
        unsigned int v2 = base[(size_t)s2 * 64 + lane];
        unsigned int v3 = base[(size_t)s3 * 64 + lane];
        unsigned int v4 = base[(size_t)s4 * 64 + lane];
        unsigned int v5 = base[(size_t)s5 * 64 + lane];
        unsigned int v6 = base[(size_t)s6 * 64 + lane];
        unsigned int v7 = base[(size_t)s7 * 64 + lane];
        unsigned int v8 = base[(size_t)s8 * 64 + lane];
        unsigned int v9 = base[(size_t)s9 * 64 + lane];
        unsigned int va = base[(size_t)sa * 64 + lane];
        unsigned int vb = base[(size_t)sb * 64 + lane];
        unsigned int vc = base[(size_t)sc * 64 + lane];
        unsigned int vd = base[(size_t)sd * 64 + lane];
        unsigned int ve = base[(size_t)se * 64 + lane];
        unsigned int vf = base[(size_t)sf * 64 + lane];
        ax += bflo(v0) + bflo(v1) + bflo(v2) + bflo(v3)
            + bflo(v4) + bflo(v5) + bflo(v6) + bflo(v7)
            + bflo(v8) + bflo(v9) + bflo(va) + bflo(vb)
            + bflo(vc) + bflo(vd) + bflo(ve) + bflo(vf);
        ay += bfhi(v0) + bfhi(v1) + bfhi(v2) + bfhi(v3)
            + bfhi(v4) + bfhi(v5) + bfhi(v6) + bfhi(v7)
            + bfhi(v8) + bfhi(v9) + bfhi(va) + bfhi(vb)
            + bfhi(vc) + bfhi(vd) + bfhi(ve) + bfhi(vf);
    }
    for (; i + 3 < e; i += 4) {
        int s0 = csr_src[i], s1 = csr_src[i + 1], s2 = csr_src[i + 2], s3 = csr_src[i + 3];
        unsigned int v0 = base[(size_t)s0 * 64 + lane];
        unsigned int v1 = base[(size_t)s1 * 64 + lane];
        unsigned int v2 = base[(size_t)s2 * 64 + lane];
        unsigned int v3 = base[(size_t)s3 * 64 + lane];
        ax += bflo(v0) + bflo(v1) + bflo(v2) + bflo(v3);
        ay += bfhi(v0) + bfhi(v1) + bfhi(v2) + bfhi(v3);
    }
    for (; i < e; ++i) {
        unsigned int v = base[(size_t)csr_src[i] * 64 + lane];
        ax += bflo(v); ay += bfhi(v);
    }
    ((unsigned int*)hb)[(size_t)node * 64 + lane] = packbf(ax, ay);
}

// ---------------- fused layer: out = relu(relu(BN(in@W1))@W2 + b2) ----------------
// R9 structure (proven): 512 thr, 128x128 tile, one Bs time-multiplexed W1->W2,
// As aliased A->H->C (wave-private rows). 68 KB LDS -> 2 blocks/CU.
__global__ __launch_bounds__(512, 4) void fused_gemm(const ushort* __restrict__ in,
                                                     ushort* __restrict__ out,
                                                     const ushort* __restrict__ Wt1,
                                                     const ushort* __restrict__ Wt2,
                                                     const float* __restrict__ fold1,
                                                     const float* __restrict__ fold2) {
    __shared__ ushort As[128 * 136];    // A tile -> H tile -> C tile (aliased)
    __shared__ ushort Bs[128 * 136];    // W1^T, then W2^T
    int t = threadIdx.x;
    int row0 = blockIdx.x * 128;        // 782 blocks, last partial (32 rows)

#pragma unroll
    for (int i = 0; i < 4; ++i) {       // stage A + W1
        int f = t + 512 * i; int m = f >> 4, g = f & 15;
        *(float4*)(As + m * 136 + g * 8) = *(const float4*)(in + (size_t)(row0 + m) * D + g * 8);
        *(float4*)(Bs + m * 136 + g * 8) = *(const float4*)(Wt1 + (size_t)m * D + g * 8);
    }
    __syncthreads();

    int lane = t & 63, wv = t >> 6;
    int quad = lane >> 4, mr = lane & 15;
    int mbase = wv * 16;
    const ushort* ap = As + (mbase + mr) * 136 + quad * 8;
    bf16x8 a0 = *(const bf16x8*)(ap);
    bf16x8 a1 = *(const bf16x8*)(ap + 32);
    bf16x8 a2 = *(const bf16x8*)(ap + 64);
    bf16x8 a3 = *(const bf16x8*)(ap + 96);

    // --- GEMM1: H = relu(BN(A@W1)) -> As own rows (in-wave DS ordering: safe)
#pragma unroll
    for (int nt = 0; nt < 8; ++nt) {
        const ushort* bq = Bs + (nt * 16 + mr) * 136 + quad * 8;
        bf16x8 b0 = *(const bf16x8*)(bq);
        bf16x8 b1 = *(const bf16x8*)(bq + 32);
        bf16x8 b2 = *(const bf16x8*)(bq + 64);
        bf16x8 b3 = *(const bf16x8*)(bq + 96);
        f32x4 acc = {0.f, 0.f, 0.f, 0.f};
        acc = __builtin_amdgcn_mfma_f32_16x16x32_bf16(a0, b0, acc, 0, 0, 0);
        acc = __builtin_amdgcn_mfma_f32_16x16x32_bf16(a1, b1, acc, 0, 0, 0);
        acc = __builtin_amdgcn_mfma_f32_16x16x32_bf16(a2, b2, acc, 0, 0, 0);
        acc = __builtin_amdgcn_mfma_f32_16x16x32_bf16(a3, b3, acc, 0, 0, 0);
        int j = nt * 16 + mr;           // C/D: col=lane&15, row=quad*4+reg (m89)
        float s = fold1[j], o = fold1[D + j];
#pragma unroll
        for (int r = 0; r < 4; ++r) {
            float z = fmaxf(fmaf(acc[r], s, o), 0.0f);
            As[(mbase + quad * 4 + r) * 136 + j] = f2bf(z);
        }
    }
    __syncthreads();                    // all waves done reading W1 from Bs

#pragma unroll
    for (int i = 0; i < 4; ++i) {       // re-stage Bs with W2
        int f = t + 512 * i; int m = f >> 4, g = f & 15;
        *(float4*)(Bs + m * 136 + g * 8) = *(const float4*)(Wt2 + (size_t)m * D + g * 8);
    }
    const ushort* hp = As + (mbase + mr) * 136 + quad * 8;
    bf16x8 h0 = *(const bf16x8*)(hp);
    bf16x8 h1 = *(const bf16x8*)(hp + 32);
    bf16x8 h2 = *(const bf16x8*)(hp + 64);
    bf16x8 h3 = *(const bf16x8*)(hp + 96);
    __syncthreads();                    // W2 staged

    // --- GEMM2: C = relu(H@W2 + b2) -> As own rows
#pragma unroll
    for (int nt = 0; nt < 8; ++nt) {
        const ushort* bq = Bs + (nt * 16 + mr) * 136 + quad * 8;
        bf16x8 b0 = *(const bf16x8*)(bq);
        bf16x8 b1 = *(const bf16x8*)(bq + 32);
        bf16x8 b2 = *(const bf16x8*)(bq + 64);
        bf16x8 b3 = *(const bf16x8*)(bq + 96);
        f32x4 acc = {0.f, 0.f, 0.f, 0.f};
        acc = __builtin_amdgcn_mfma_f32_16x16x32_bf16(h0, b0, acc, 0, 0, 0);
        acc = __builtin_amdgcn_mfma_f32_16x16x32_bf16(h1, b1, acc, 0, 0, 0);
        acc = __builtin_amdgcn_mfma_f32_16x16x32_bf16(h2, b2, acc, 0, 0, 0);
        acc = __builtin_amdgcn_mfma_f32_16x16x32_bf16(h3, b3, acc, 0, 0, 0);
        int j = nt * 16 + mr;
        float o = fold2[D + j];
#pragma unroll
        for (int r = 0; r < 4; ++r) {
            float z = fmaxf(acc[r] + o, 0.0f);
            As[(mbase + quad * 4 + r) * 136 + j] = f2bf(z);
        }
    }
    __syncthreads();

#pragma unroll
    for (int i = 0; i < 8; ++i) {       // coalesced copy-out, float2 = 4 bf16
        int f = t + 512 * i; int lr = f >> 5, g = f & 31;
        if (row0 + lr < N_NODES)
            *(float2*)(out + (size_t)(row0 + lr) * D + g * 4) =
                *(const float2*)(As + lr * 136 + g * 4);
    }
}

// ---------------- pooling + head fused: out[r] = relu(pool(r)@W1+b1)@W2+b2 ----------------
__global__ __launch_bounds__(128) void poolhead_kernel(const ushort* __restrict__ xb,
                                                       const int* __restrict__ gstart,
                                                       const float* __restrict__ W1,
                                                       const float* __restrict__ b1,
                                                       const float* __restrict__ W2,
                                                       const float* __restrict__ b2,
                                                       float* __restrict__ out) {
    __shared__ float row[128];
    __shared__ float t1[128];
    int r = blockIdx.x, j = threadIdx.x;
    float acc = 0.0f;
    int b = gstart[r], e = gstart[r + 1];
    for (int i = b; i < e; ++i)
        acc += __uint_as_float(((unsigned int)xb[(size_t)i * D + j]) << 16);
    row[j] = acc;
    __syncthreads();
    float a1 = b1[j];
    for (int k = 0; k < D; ++k) a1 = fmaf(row[k], W1[k * D + j], a1);
    t1[j] = fmaxf(a1, 0.0f);
    __syncthreads();
    float a2 = b2[j];
    for (int k = 0; k < D; ++k) a2 = fmaf(t1[k], W2[k * D + j], a2);
    out[r * D + j] = a2;
}

// ---------------- launcher ----------------
extern "C" void kernel_launch(void* const* d_in, const int* in_sizes, int n_in,
                              void* d_out, int out_size, void* d_ws, size_t ws_size,
                              hipStream_t stream) {
    const float* x        = (const float*)d_in[0];
    const int*   ei       = (const int*)d_in[1];
    const int*   src      = ei;
    const int*   dst      = ei + N_EDGES;
    const int*   batch    = (const int*)d_in[2];
    const float* conv_W1  = (const float*)d_in[3];
    const float* conv_b1  = (const float*)d_in[4];
    const float* bn_gamma = (const float*)d_in[5];
    const float* bn_beta  = (const float*)d_in[6];
    const float* bn_mean  = (const float*)d_in[7];
    const float* bn_var   = (const float*)d_in[8];
    const float* conv_W2  = (const float*)d_in[9];
    const float* conv_b2  = (const float*)d_in[10];
    const float* head_W1  = (const float*)d_in[11];
    const float* head_b1  = (const float*)d_in[12];
    const float* head_W2  = (const float*)d_in[13];
    const float* head_b2  = (const float*)d_in[14];
    float* out = (float*)d_out;

    char* ws = (char*)d_ws;
    size_t off = 0;
    auto alloc = [&](size_t bytes) -> void* {
        void* p = ws + off;
        off = (off + bytes + 255) & ~(size_t)255;
        return p;
    };
    const size_t NODE_BUF = (size_t)(N_NODES + 128) * D * sizeof(ushort);
    ushort* buf0    = (ushort*)alloc(NODE_BUF);
    ushort* buf1    = (ushort*)alloc(NODE_BUF);
    ushort* Wt      = (ushort*)alloc((size_t)6 * D * D * sizeof(ushort));
    float*  folds   = (float*)alloc((size_t)6 * 2 * D * sizeof(float));
    unsigned int* squeue = (unsigned int*)alloc((size_t)FNSLICE * FSLICE_CAP * sizeof(unsigned int));
    int*   csr_src  = (int*)alloc((size_t)N_EDGES * sizeof(int));
    int*   offsets  = (int*)alloc((size_t)(N_NODES + 1) * sizeof(int));
    int*   slice_tail = (int*)alloc((size_t)FNSLICE * sizeof(int));
    int*   gstart   = (int*)alloc((size_t)(N_GRAPHS + 1) * sizeof(int));

    setup_kernel<<<SETUP_GRID, 256, 0, stream>>>(
        x, buf0, conv_W1, conv_W2, Wt,
        conv_b1, bn_gamma, bn_beta, bn_mean, bn_var, conv_b2, folds,
        batch, gstart, slice_tail, offsets);
    compact_kernel<<<CGRID, 256, 0, stream>>>(src, dst, squeue, slice_tail);
    fill_local<<<FNSLICE, 1024, 0, stream>>>(squeue, slice_tail, offsets, csr_src);

    const int FUSED_GRID = (N_NODES + 127) / 128;   // 782
    for (int l = 0; l < 3; ++l) {
        gather_bf16<<<N_NODES / 4, 256, 0, stream>>>(buf0, offsets, csr_src, buf1);
        fused_gemm<<<FUSED_GRID, 512, 0, stream>>>(buf1, buf0,
            Wt + (size_t)(2 * l) * D * D, Wt + (size_t)(2 * l + 1) * D * D,
            folds + (size_t)(2 * l) * 2 * D, folds + (size_t)(2 * l + 1) * 2 * D);
    }

    poolhead_kernel<<<N_GRAPHS, 128, 0, stream>>>(buf0, gstart, head_W1, head_b1,
                                                  head_W2, head_b2, out);
}

// Round 12
// 446.535 us; speedup vs baseline: 1.0913x; 1.0010x over previous
//
#include <hip/hip_runtime.h>

#define N_NODES  100000
#define N_EDGES  1600000
#define N_GRAPHS 1024
#define D        128
#define BN_EPS   1e-5f

// --- atomic-free CSR build geometry ---
#define FNSLICE      98                  // ceil(100000/1024) node slices
#define FSLICE_NODES 1024                // nodes per slice (d>>10)
#define FSLICE_CAP   20480               // queue cap: mean 16384, sigma~127
#define QCAP         96                  // per-block LDS bin: mean 41, +12 sigma
#define CCHUNK       4000
#define CGRID        400                 // 400*4000 == N_EDGES

// --- setup_kernel block ranges (256 thr each) ---
#define CVT_BLOCKS   6250                // 100000*128 / (256*8)
#define PW_BLOCKS    384                 // 6*128*128 / 256
#define FOLD_BLOCKS  3                   // 6*128 / 256
#define GST_BLOCKS   5                   // 1025 / 256
#define SETUP_GRID   (CVT_BLOCKS + PW_BLOCKS + FOLD_BLOCKS + GST_BLOCKS + 1)

#define ZROW N_NODES                     // dedicated all-zero row for tail padding

typedef short bf16x8 __attribute__((ext_vector_type(8)));
typedef float f32x4  __attribute__((ext_vector_type(4)));

__device__ __forceinline__ ushort f2bf(float f) {        // RNE fp32->bf16
    unsigned int b = __float_as_uint(f);
    return (ushort)((b + 0x7fffu + ((b >> 16) & 1u)) >> 16);
}
__device__ __forceinline__ float bflo(unsigned int u) { return __uint_as_float(u << 16); }
__device__ __forceinline__ float bfhi(unsigned int u) { return __uint_as_float(u & 0xffff0000u); }
__device__ __forceinline__ unsigned int packbf(float x, float y) {
    return (unsigned int)f2bf(x) | ((unsigned int)f2bf(y) << 16);
}

// ---------------- setup: cvt_x + prep_w + folds + gstart + misc, one launch ----------------
__global__ __launch_bounds__(256) void setup_kernel(
        const float* __restrict__ x, ushort* __restrict__ xb,
        const float* __restrict__ W1, const float* __restrict__ W2,
        ushort* __restrict__ Wt,
        const float* __restrict__ b1, const float* __restrict__ gamma,
        const float* __restrict__ beta, const float* __restrict__ mean,
        const float* __restrict__ var, const float* __restrict__ b2,
        float* __restrict__ folds,
        const int* __restrict__ batch, int* __restrict__ gstart,
        int* __restrict__ slice_tail, int* __restrict__ offsets) {
    int b = blockIdx.x, t = threadIdx.x;
    if (b < CVT_BLOCKS) {                                  // x -> bf16
        size_t i = ((size_t)b * 256 + t) * 8;
        float4 v0 = *(const float4*)(x + i);
        float4 v1 = *(const float4*)(x + i + 4);
        uint4 o;
        o.x = packbf(v0.x, v0.y); o.y = packbf(v0.z, v0.w);
        o.z = packbf(v1.x, v1.y); o.w = packbf(v1.z, v1.w);
        *(uint4*)(xb + i) = o;
    } else if (b < CVT_BLOCKS + PW_BLOCKS) {               // W -> bf16 transposed
        int idx = (b - CVT_BLOCKS) * 256 + t;              // [0, 6*16384)
        int i = idx >> 14, r = idx & 16383;
        int n = r >> 7, k = r & 127, l = i >> 1;
        const float* W = (i & 1) ? (W2 + (size_t)l * D * D) : (W1 + (size_t)l * D * D);
        Wt[idx] = f2bf(W[k * D + n]);
    } else if (b < CVT_BLOCKS + PW_BLOCKS + FOLD_BLOCKS) { // BN folds
        int idx = (b - CVT_BLOCKS - PW_BLOCKS) * 256 + t;  // [0, 768)
        if (idx < 6 * D) {
            int i = idx >> 7, j = idx & 127, l = i >> 1;
            float s, o;
            if ((i & 1) == 0) {
                float sv = gamma[l * D + j] * rsqrtf(var[l * D + j] + BN_EPS);
                s = sv;
                o = (b1[l * D + j] - mean[l * D + j]) * sv + beta[l * D + j];
            } else {
                s = 1.0f;
                o = b2[l * D + j];
            }
            folds[(size_t)i * 2 * D + j]     = s;
            folds[(size_t)i * 2 * D + D + j] = o;
        }
    } else if (b < CVT_BLOCKS + PW_BLOCKS + FOLD_BLOCKS + GST_BLOCKS) {  // gstart
        int g = (b - CVT_BLOCKS - PW_BLOCKS - FOLD_BLOCKS) * 256 + t;
        if (g <= N_GRAPHS) {
            int lo = 0, hi = N_NODES;
            while (lo < hi) {
                int mid = (lo + hi) >> 1;
                if (batch[mid] < g) lo = mid + 1; else hi = mid;
            }
            gstart[g] = lo;
        }
    } else {                                               // misc
        if (t < FNSLICE) slice_tail[t] = 0;
        if (t < 64)                                        // zero ZROW (tail pad target)
            ((unsigned int*)xb)[(size_t)ZROW * 64 + t] = 0u;
        if (t == 255) offsets[N_NODES] = N_EDGES;
    }
}

// ---------------- CSR pass 1: bin edges by 1024-node slice (LDS), bulk-append ----------------
__global__ __launch_bounds__(256) void compact_kernel(const int* __restrict__ src,
                                                      const int* __restrict__ dst,
                                                      unsigned int* __restrict__ squeue,
                                                      int* __restrict__ slice_tail) {
    __shared__ unsigned int qbuf[FNSLICE * QCAP];   // 37.6 KB
    __shared__ int qcnt[FNSLICE];
    __shared__ int qbase[FNSLICE];
    int t = threadIdx.x;
    for (int i = t; i < FNSLICE; i += 256) qcnt[i] = 0;
    __syncthreads();
    int e0 = blockIdx.x * CCHUNK;
    int eend = e0 + CCHUNK; if (eend > N_EDGES) eend = N_EDGES;
    for (int e = e0 + t; e < eend; e += 256) {
        int d = dst[e], s = src[e];
        int sl = d >> 10;
        unsigned int pk = ((unsigned int)(d & 1023) << 17) | (unsigned int)s;
        int pos = atomicAdd(&qcnt[sl], 1);
        if (pos < QCAP) qbuf[sl * QCAP + pos] = pk;
        else {  // ~never (12-sigma): direct spill, still correct
            int gp = atomicAdd(&slice_tail[sl], 1);
            squeue[(size_t)sl * FSLICE_CAP + gp] = pk;
        }
    }
    __syncthreads();
    for (int i = t; i < FNSLICE; i += 256) {
        int n = qcnt[i]; if (n > QCAP) n = QCAP;
        qbase[i] = atomicAdd(&slice_tail[i], n);
    }
    __syncthreads();
    int wv = t >> 6, ln = t & 63;
    for (int sl = wv; sl < FNSLICE; sl += 4) {
        int n = qcnt[sl]; if (n > QCAP) n = QCAP;
        int gb = qbase[sl];
        for (int i = ln; i < n; i += 64)
            squeue[(size_t)sl * FSLICE_CAP + gb + i] = qbuf[sl * QCAP + i];
    }
}

// ---------------- CSR pass 2: per-slice hist -> scan -> fill, LDS atomics only ----------------
__global__ __launch_bounds__(1024) void fill_local(const unsigned int* __restrict__ squeue,
                                                   const int* __restrict__ slice_tail,
                                                   int* __restrict__ offsets,
                                                   int* __restrict__ csr_src) {
    __shared__ int hist[FSLICE_NODES];
    __shared__ int cur[FSLICE_NODES];
    __shared__ int sbase[128];
    __shared__ int wsum[16];
    int sl = blockIdx.x, t = threadIdx.x;
    int n = slice_tail[sl];
    if (t < 128) sbase[t] = (t < FNSLICE) ? slice_tail[t] : 0;
    hist[t] = 0;
    __syncthreads();
    for (int off = 1; off < 128; off <<= 1) {      // in-block scan of slice totals
        int u = (t < 128 && t >= off) ? sbase[t - off] : 0;
        __syncthreads();
        if (t < 128) sbase[t] += u;
        __syncthreads();
    }
    int gbase = (sl == 0) ? 0 : sbase[sl - 1];
    size_t qb = (size_t)sl * FSLICE_CAP;
    for (int i = t; i < n; i += 1024)
        atomicAdd(&hist[squeue[qb + i] >> 17], 1);
    __syncthreads();
    int c = hist[t];
    int lane = t & 63, w = t >> 6;
    int sc = c;
#pragma unroll
    for (int off = 1; off < 64; off <<= 1) {       // wave-inclusive scan
        int u = __shfl_up(sc, off, 64);
        if (lane >= off) sc += u;
    }
    if (lane == 63) wsum[w] = sc;
    __syncthreads();
    if (t < 16) {                                  // scan the 16 wave sums
        int ws = wsum[t];
        int s2 = ws;
#pragma unroll
        for (int off = 1; off < 16; off <<= 1) {
            int u = __shfl_up(s2, off, 16);
            if (t >= off) s2 += u;
        }
        wsum[t] = s2 - ws;                         // exclusive wave prefix
    }
    __syncthreads();
    int gslot = gbase + sc + wsum[w] - c;          // global exclusive slot
    cur[t] = gslot;
    int node = sl * FSLICE_NODES + t;
    if (node < N_NODES) offsets[node] = gslot;
    __syncthreads();
    for (int i = t; i < n; i += 1024) {
        unsigned int p = squeue[qb + i];
        int slot = atomicAdd(&cur[p >> 17], 1);    // LDS atomic
        csr_src[slot] = (int)(p & 0x1FFFFu);
    }
}

// ---------------- aggregation: 16 lanes x dwordx4 per row, 4 edges / wave-inst ----------------
// Per 32-edge-slot chunk: 8 uint4 loads (8 KB in flight/wave, 2x the R11 dword
// version) at 4x fewer VMEM insts. Tail slots clamped to ZROW (zeroed in setup,
// L1-resident after first touch). Cross-sub combine: 2 shfl_xor per accumulator.
__global__ __launch_bounds__(256) void gather_bf16(const ushort* __restrict__ xb,
                                                   const int* __restrict__ offsets,
                                                   const int* __restrict__ csr_src,
                                                   ushort* __restrict__ hb) {
    int wv = threadIdx.x >> 6, lane = threadIdx.x & 63;
    int node = blockIdx.x * 4 + wv;           // 25000*4 == N_NODES
    int sub = lane >> 4;                      // which edge of the quad (0..3)
    int col = lane & 15;                      // 16B chunk within the 256B row
    const uint4* base16 = (const uint4*)xb;
    float a0 = 0.f, a1 = 0.f, a2 = 0.f, a3 = 0.f,
          a4 = 0.f, a5 = 0.f, a6 = 0.f, a7 = 0.f;
    int b = offsets[node], e = offsets[node + 1];
    for (int i = b; i < e; i += 32) {         // 32 edge slots, 8 insts
#pragma unroll
        for (int q = 0; q < 8; ++q) {
            int idx = i + q * 4 + sub;
            int idc = idx < e ? idx : e - 1;  // in-bounds (loop entered => e > b)
            int s = csr_src[idc];
            s = idx < e ? s : ZROW;           // pad to the zero row
            uint4 v = base16[(size_t)s * 16 + col];
            a0 += bflo(v.x); a1 += bfhi(v.x);
            a2 += bflo(v.y); a3 += bfhi(v.y);
            a4 += bflo(v.z); a5 += bfhi(v.z);
            a6 += bflo(v.w); a7 += bfhi(v.w);
        }
    }
    // combine the 4 sub-partials (lanes col, col+16, col+32, col+48)
#define GIN_RED(A) A += __shfl_xor(A, 16); A += __shfl_xor(A, 32);
    GIN_RED(a0) GIN_RED(a1) GIN_RED(a2) GIN_RED(a3)
    GIN_RED(a4) GIN_RED(a5) GIN_RED(a6) GIN_RED(a7)
#undef GIN_RED
    // + self row (same addr for all sub lanes -> broadcast fetch)
    uint4 sv = base16[(size_t)node * 16 + col];
    a0 += bflo(sv.x); a1 += bfhi(sv.x);
    a2 += bflo(sv.y); a3 += bfhi(sv.y);
    a4 += bflo(sv.z); a5 += bfhi(sv.z);
    a6 += bflo(sv.w); a7 += bfhi(sv.w);
    if (sub == 0) {
        uint4 o;
        o.x = packbf(a0, a1); o.y = packbf(a2, a3);
        o.z = packbf(a4, a5); o.w = packbf(a6, a7);
        ((uint4*)hb)[(size_t)node * 16 + col] = o;
    }
}

// ---------------- fused layer: out = relu(relu(BN(in@W1))@W2 + b2) ----------------
// R9 structure (proven): 512 thr, 128x128 tile, one Bs time-multiplexed W1->W2,
// As aliased A->H->C (wave-private rows). 68 KB LDS -> 2 blocks/CU.
__global__ __launch_bounds__(512, 4) void fused_gemm(const ushort* __restrict__ in,
                                                     ushort* __restrict__ out,
                                                     const ushort* __restrict__ Wt1,
                                                     const ushort* __restrict__ Wt2,
                                                     const float* __restrict__ fold1,
                                                     const float* __restrict__ fold2) {
    __shared__ ushort As[128 * 136];    // A tile -> H tile -> C tile (aliased)
    __shared__ ushort Bs[128 * 136];    // W1^T, then W2^T
    int t = threadIdx.x;
    int row0 = blockIdx.x * 128;        // 782 blocks, last partial (32 rows)

#pragma unroll
    for (int i = 0; i < 4; ++i) {       // stage A + W1
        int f = t + 512 * i; int m = f >> 4, g = f & 15;
        *(float4*)(As + m * 136 + g * 8) = *(const float4*)(in + (size_t)(row0 + m) * D + g * 8);
        *(float4*)(Bs + m * 136 + g * 8) = *(const float4*)(Wt1 + (size_t)m * D + g * 8);
    }
    __syncthreads();

    int lane = t & 63, wv = t >> 6;
    int quad = lane >> 4, mr = lane & 15;
    int mbase = wv * 16;
    const ushort* ap = As + (mbase + mr) * 136 + quad * 8;
    bf16x8 a0 = *(const bf16x8*)(ap);
    bf16x8 a1 = *(const bf16x8*)(ap + 32);
    bf16x8 a2 = *(const bf16x8*)(ap + 64);
    bf16x8 a3 = *(const bf16x8*)(ap + 96);

    // --- GEMM1: H = relu(BN(A@W1)) -> As own rows (in-wave DS ordering: safe)
#pragma unroll
    for (int nt = 0; nt < 8; ++nt) {
        const ushort* bq = Bs + (nt * 16 + mr) * 136 + quad * 8;
        bf16x8 b0 = *(const bf16x8*)(bq);
        bf16x8 b1 = *(const bf16x8*)(bq + 32);
        bf16x8 b2 = *(const bf16x8*)(bq + 64);
        bf16x8 b3 = *(const bf16x8*)(bq + 96);
        f32x4 acc = {0.f, 0.f, 0.f, 0.f};
        acc = __builtin_amdgcn_mfma_f32_16x16x32_bf16(a0, b0, acc, 0, 0, 0);
        acc = __builtin_amdgcn_mfma_f32_16x16x32_bf16(a1, b1, acc, 0, 0, 0);
        acc = __builtin_amdgcn_mfma_f32_16x16x32_bf16(a2, b2, acc, 0, 0, 0);
        acc = __builtin_amdgcn_mfma_f32_16x16x32_bf16(a3, b3, acc, 0, 0, 0);
        int j = nt * 16 + mr;           // C/D: col=lane&15, row=quad*4+reg (m89)
        float s = fold1[j], o = fold1[D + j];
#pragma unroll
        for (int r = 0; r < 4; ++r) {
            float z = fmaxf(fmaf(acc[r], s, o), 0.0f);
            As[(mbase + quad * 4 + r) * 136 + j] = f2bf(z);
        }
    }
    __syncthreads();                    // all waves done reading W1 from Bs

#pragma unroll
    for (int i = 0; i < 4; ++i) {       // re-stage Bs with W2
        int f = t + 512 * i; int m = f >> 4, g = f & 15;
        *(float4*)(Bs + m * 136 + g * 8) = *(const float4*)(Wt2 + (size_t)m * D + g * 8);
    }
    const ushort* hp = As + (mbase + mr) * 136 + quad * 8;
    bf16x8 h0 = *(const bf16x8*)(hp);
    bf16x8 h1 = *(const bf16x8*)(hp + 32);
    bf16x8 h2 = *(const bf16x8*)(hp + 64);
    bf16x8 h3 = *(const bf16x8*)(hp + 96);
    __syncthreads();                    // W2 staged

    // --- GEMM2: C = relu(H@W2 + b2) -> As own rows
#pragma unroll
    for (int nt = 0; nt < 8; ++nt) {
        const ushort* bq = Bs + (nt * 16 + mr) * 136 + quad * 8;
        bf16x8 b0 = *(const bf16x8*)(bq);
        bf16x8 b1 = *(const bf16x8*)(bq + 32);
        bf16x8 b2 = *(const bf16x8*)(bq + 64);
        bf16x8 b3 = *(const bf16x8*)(bq + 96);
        f32x4 acc = {0.f, 0.f, 0.f, 0.f};
        acc = __builtin_amdgcn_mfma_f32_16x16x32_bf16(h0, b0, acc, 0, 0, 0);
        acc = __builtin_amdgcn_mfma_f32_16x16x32_bf16(h1, b1, acc, 0, 0, 0);
        acc = __builtin_amdgcn_mfma_f32_16x16x32_bf16(h2, b2, acc, 0, 0, 0);
        acc = __builtin_amdgcn_mfma_f32_16x16x32_bf16(h3, b3, acc, 0, 0, 0);
        int j = nt * 16 + mr;
        float o = fold2[D + j];
#pragma unroll
        for (int r = 0; r < 4; ++r) {
            float z = fmaxf(acc[r] + o, 0.0f);
            As[(mbase + quad * 4 + r) * 136 + j] = f2bf(z);
        }
    }
    __syncthreads();

#pragma unroll
    for (int i = 0; i < 8; ++i) {       // coalesced copy-out, float2 = 4 bf16
        int f = t + 512 * i; int lr = f >> 5, g = f & 31;
        if (row0 + lr < N_NODES)
            *(float2*)(out + (size_t)(row0 + lr) * D + g * 4) =
                *(const float2*)(As + lr * 136 + g * 4);
    }
}

// ---------------- pooling + head fused: out[r] = relu(pool(r)@W1+b1)@W2+b2 ----------------
__global__ __launch_bounds__(128) void poolhead_kernel(const ushort* __restrict__ xb,
                                                       const int* __restrict__ gstart,
                                                       const float* __restrict__ W1,
                                                       const float* __restrict__ b1,
                                                       const float* __restrict__ W2,
                                                       const float* __restrict__ b2,
                                                       float* __restrict__ out) {
    __shared__ float row[128];
    __shared__ float t1[128];
    int r = blockIdx.x, j = threadIdx.x;
    float acc = 0.0f;
    int b = gstart[r], e = gstart[r + 1];
    for (int i = b; i < e; ++i)
        acc += __uint_as_float(((unsigned int)xb[(size_t)i * D + j]) << 16);
    row[j] = acc;
    __syncthreads();
    float a1 = b1[j];
    for (int k = 0; k < D; ++k) a1 = fmaf(row[k], W1[k * D + j], a1);
    t1[j] = fmaxf(a1, 0.0f);
    __syncthreads();
    float a2 = b2[j];
    for (int k = 0; k < D; ++k) a2 = fmaf(t1[k], W2[k * D + j], a2);
    out[r * D + j] = a2;
}

// ---------------- launcher ----------------
extern "C" void kernel_launch(void* const* d_in, const int* in_sizes, int n_in,
                              void* d_out, int out_size, void* d_ws, size_t ws_size,
                              hipStream_t stream) {
    const float* x        = (const float*)d_in[0];
    const int*   ei       = (const int*)d_in[1];
    const int*   src      = ei;
    const int*   dst      = ei + N_EDGES;
    const int*   batch    = (const int*)d_in[2];
    const float* conv_W1  = (const float*)d_in[3];
    const float* conv_b1  = (const float*)d_in[4];
    const float* bn_gamma = (const float*)d_in[5];
    const float* bn_beta  = (const float*)d_in[6];
    const float* bn_mean  = (const float*)d_in[7];
    const float* bn_var   = (const float*)d_in[8];
    const float* conv_W2  = (const float*)d_in[9];
    const float* conv_b2  = (const float*)d_in[10];
    const float* head_W1  = (const float*)d_in[11];
    const float* head_b1  = (const float*)d_in[12];
    const float* head_W2  = (const float*)d_in[13];
    const float* head_b2  = (const float*)d_in[14];
    float* out = (float*)d_out;

    char* ws = (char*)d_ws;
    size_t off = 0;
    auto alloc = [&](size_t bytes) -> void* {
        void* p = ws + off;
        off = (off + bytes + 255) & ~(size_t)255;
        return p;
    };
    const size_t NODE_BUF = (size_t)(N_NODES + 128) * D * sizeof(ushort);
    ushort* buf0    = (ushort*)alloc(NODE_BUF);
    ushort* buf1    = (ushort*)alloc(NODE_BUF);
    ushort* Wt      = (ushort*)alloc((size_t)6 * D * D * sizeof(ushort));
    float*  folds   = (float*)alloc((size_t)6 * 2 * D * sizeof(float));
    unsigned int* squeue = (unsigned int*)alloc((size_t)FNSLICE * FSLICE_CAP * sizeof(unsigned int));
    int*   csr_src  = (int*)alloc((size_t)(N_EDGES + 64) * sizeof(int));
    int*   offsets  = (int*)alloc((size_t)(N_NODES + 1) * sizeof(int));
    int*   slice_tail = (int*)alloc((size_t)FNSLICE * sizeof(int));
    int*   gstart   = (int*)alloc((size_t)(N_GRAPHS + 1) * sizeof(int));

    setup_kernel<<<SETUP_GRID, 256, 0, stream>>>(
        x, buf0, conv_W1, conv_W2, Wt,
        conv_b1, bn_gamma, bn_beta, bn_mean, bn_var, conv_b2, folds,
        batch, gstart, slice_tail, offsets);
    compact_kernel<<<CGRID, 256, 0, stream>>>(src, dst, squeue, slice_tail);
    fill_local<<<FNSLICE, 1024, 0, stream>>>(squeue, slice_tail, offsets, csr_src);

    const int FUSED_GRID = (N_NODES + 127) / 128;   // 782
    for (int l = 0; l < 3; ++l) {
        gather_bf16<<<N_NODES / 4, 256, 0, stream>>>(buf0, offsets, csr_src, buf1);
        fused_gemm<<<FUSED_GRID, 512, 0, stream>>>(buf1, buf0,
            Wt + (size_t)(2 * l) * D * D, Wt + (size_t)(2 * l + 1) * D * D,
            folds + (size_t)(2 * l) * 2 * D, folds + (size_t)(2 * l + 1) * 2 * D);
    }

    poolhead_kernel<<<N_GRAPHS, 128, 0, stream>>>(buf0, gstart, head_W1, head_b1,
                                                  head_W2, head_b2, out);
}

// Round 13
// 444.380 us; speedup vs baseline: 1.0965x; 1.0048x over previous
//
#include <hip/hip_runtime.h>

#define N_NODES  100000
#define N_EDGES  1600000
#define N_GRAPHS 1024
#define D        128
#define BN_EPS   1e-5f

// --- atomic-free CSR build geometry ---
#define FNSLICE      98                  // ceil(100000/1024) node slices
#define FSLICE_NODES 1024                // nodes per slice (d>>10)
#define FSLICE_CAP   20480               // queue cap: mean 16384, sigma~127
#define QCAP         96                  // per-block LDS bin: mean 41, +12 sigma
#define CCHUNK       4000
#define CGRID        400                 // 400*4000 == N_EDGES

// --- setup_kernel block ranges (256 thr each) ---
#define CVT_BLOCKS   6250                // 100000*128 / (256*8)
#define PW_BLOCKS    384                 // 6*128*128 / 256
#define FOLD_BLOCKS  3                   // 6*128 / 256
#define GST_BLOCKS   5                   // 1025 / 256
#define SETUP_GRID   (CVT_BLOCKS + PW_BLOCKS + FOLD_BLOCKS + GST_BLOCKS + 1)

typedef short bf16x8 __attribute__((ext_vector_type(8)));
typedef float f32x4  __attribute__((ext_vector_type(4)));

__device__ __forceinline__ ushort f2bf(float f) {        // RNE fp32->bf16
    unsigned int b = __float_as_uint(f);
    return (ushort)((b + 0x7fffu + ((b >> 16) & 1u)) >> 16);
}
__device__ __forceinline__ float bflo(unsigned int u) { return __uint_as_float(u << 16); }
__device__ __forceinline__ float bfhi(unsigned int u) { return __uint_as_float(u & 0xffff0000u); }
__device__ __forceinline__ unsigned int packbf(float x, float y) {
    return (unsigned int)f2bf(x) | ((unsigned int)f2bf(y) << 16);
}

// ---------------- setup: cvt_x + prep_w + folds + gstart + misc, one launch ----------------
__global__ __launch_bounds__(256) void setup_kernel(
        const float* __restrict__ x, ushort* __restrict__ xb,
        const float* __restrict__ W1, const float* __restrict__ W2,
        ushort* __restrict__ Wt,
        const float* __restrict__ b1, const float* __restrict__ gamma,
        const float* __restrict__ beta, const float* __restrict__ mean,
        const float* __restrict__ var, const float* __restrict__ b2,
        float* __restrict__ folds,
        const int* __restrict__ batch, int* __restrict__ gstart,
        int* __restrict__ slice_tail, int* __restrict__ offsets) {
    int b = blockIdx.x, t = threadIdx.x;
    if (b < CVT_BLOCKS) {                                  // x -> bf16
        size_t i = ((size_t)b * 256 + t) * 8;
        float4 v0 = *(const float4*)(x + i);
        float4 v1 = *(const float4*)(x + i + 4);
        uint4 o;
        o.x = packbf(v0.x, v0.y); o.y = packbf(v0.z, v0.w);
        o.z = packbf(v1.x, v1.y); o.w = packbf(v1.z, v1.w);
        *(uint4*)(xb + i) = o;
    } else if (b < CVT_BLOCKS + PW_BLOCKS) {               // W -> bf16 transposed
        int idx = (b - CVT_BLOCKS) * 256 + t;              // [0, 6*16384)
        int i = idx >> 14, r = idx & 16383;
        int n = r >> 7, k = r & 127, l = i >> 1;
        const float* W = (i & 1) ? (W2 + (size_t)l * D * D) : (W1 + (size_t)l * D * D);
        Wt[idx] = f2bf(W[k * D + n]);
    } else if (b < CVT_BLOCKS + PW_BLOCKS + FOLD_BLOCKS) { // BN folds
        int idx = (b - CVT_BLOCKS - PW_BLOCKS) * 256 + t;  // [0, 768)
        if (idx < 6 * D) {
            int i = idx >> 7, j = idx & 127, l = i >> 1;
            float s, o;
            if ((i & 1) == 0) {
                float sv = gamma[l * D + j] * rsqrtf(var[l * D + j] + BN_EPS);
                s = sv;
                o = (b1[l * D + j] - mean[l * D + j]) * sv + beta[l * D + j];
            } else {
                s = 1.0f;
                o = b2[l * D + j];
            }
            folds[(size_t)i * 2 * D + j]     = s;
            folds[(size_t)i * 2 * D + D + j] = o;
        }
    } else if (b < CVT_BLOCKS + PW_BLOCKS + FOLD_BLOCKS + GST_BLOCKS) {  // gstart
        int g = (b - CVT_BLOCKS - PW_BLOCKS - FOLD_BLOCKS) * 256 + t;
        if (g <= N_GRAPHS) {
            int lo = 0, hi = N_NODES;
            while (lo < hi) {
                int mid = (lo + hi) >> 1;
                if (batch[mid] < g) lo = mid + 1; else hi = mid;
            }
            gstart[g] = lo;
        }
    } else {                                               // misc
        if (t < FNSLICE) slice_tail[t] = 0;
        if (t == 255) offsets[N_NODES] = N_EDGES;
    }
}

// ---------------- CSR pass 1: bin edges by 1024-node slice (LDS), bulk-append ----------------
__global__ __launch_bounds__(256) void compact_kernel(const int* __restrict__ src,
                                                      const int* __restrict__ dst,
                                                      unsigned int* __restrict__ squeue,
                                                      int* __restrict__ slice_tail) {
    __shared__ unsigned int qbuf[FNSLICE * QCAP];   // 37.6 KB
    __shared__ int qcnt[FNSLICE];
    __shared__ int qbase[FNSLICE];
    int t = threadIdx.x;
    for (int i = t; i < FNSLICE; i += 256) qcnt[i] = 0;
    __syncthreads();
    int e0 = blockIdx.x * CCHUNK;
    int eend = e0 + CCHUNK; if (eend > N_EDGES) eend = N_EDGES;
    for (int e = e0 + t; e < eend; e += 256) {
        int d = dst[e], s = src[e];
        int sl = d >> 10;
        unsigned int pk = ((unsigned int)(d & 1023) << 17) | (unsigned int)s;
        int pos = atomicAdd(&qcnt[sl], 1);
        if (pos < QCAP) qbuf[sl * QCAP + pos] = pk;
        else {  // ~never (12-sigma): direct spill, still correct
            int gp = atomicAdd(&slice_tail[sl], 1);
            squeue[(size_t)sl * FSLICE_CAP + gp] = pk;
        }
    }
    __syncthreads();
    for (int i = t; i < FNSLICE; i += 256) {
        int n = qcnt[i]; if (n > QCAP) n = QCAP;
        qbase[i] = atomicAdd(&slice_tail[i], n);
    }
    __syncthreads();
    int wv = t >> 6, ln = t & 63;
    for (int sl = wv; sl < FNSLICE; sl += 4) {
        int n = qcnt[sl]; if (n > QCAP) n = QCAP;
        int gb = qbase[sl];
        for (int i = ln; i < n; i += 64)
            squeue[(size_t)sl * FSLICE_CAP + gb + i] = qbuf[sl * QCAP + i];
    }
}

// ---------------- CSR pass 2: per-slice hist -> scan -> fill, LDS atomics only ----------------
__global__ __launch_bounds__(1024) void fill_local(const unsigned int* __restrict__ squeue,
                                                   const int* __restrict__ slice_tail,
                                                   int* __restrict__ offsets,
                                                   int* __restrict__ csr_src) {
    __shared__ int hist[FSLICE_NODES];
    __shared__ int cur[FSLICE_NODES];
    __shared__ int sbase[128];
    __shared__ int wsum[16];
    int sl = blockIdx.x, t = threadIdx.x;
    int n = slice_tail[sl];
    if (t < 128) sbase[t] = (t < FNSLICE) ? slice_tail[t] : 0;
    hist[t] = 0;
    __syncthreads();
    for (int off = 1; off < 128; off <<= 1) {      // in-block scan of slice totals
        int u = (t < 128 && t >= off) ? sbase[t - off] : 0;
        __syncthreads();
        if (t < 128) sbase[t] += u;
        __syncthreads();
    }
    int gbase = (sl == 0) ? 0 : sbase[sl - 1];
    size_t qb = (size_t)sl * FSLICE_CAP;
    for (int i = t; i < n; i += 1024)
        atomicAdd(&hist[squeue[qb + i] >> 17], 1);
    __syncthreads();
    int c = hist[t];
    int lane = t & 63, w = t >> 6;
    int sc = c;
#pragma unroll
    for (int off = 1; off < 64; off <<= 1) {       // wave-inclusive scan
        int u = __shfl_up(sc, off, 64);
        if (lane >= off) sc += u;
    }
    if (lane == 63) wsum[w] = sc;
    __syncthreads();
    if (t < 16) {                                  // scan the 16 wave sums
        int ws = wsum[t];
        int s2 = ws;
#pragma unroll
        for (int off = 1; off < 16; off <<= 1) {
            int u = __shfl_up(s2, off, 16);
            if (t >= off) s2 += u;
        }
        wsum[t] = s2 - ws;                         // exclusive wave prefix
    }
    __syncthreads();
    int gslot = gbase + sc + wsum[w] - c;          // global exclusive slot
    cur[t] = gslot;
    int node = sl * FSLICE_NODES + t;
    if (node < N_NODES) offsets[node] = gslot;
    __syncthreads();
    for (int i = t; i < n; i += 1024) {
        unsigned int p = squeue[qb + i];
        int slot = atomicAdd(&cur[p >> 17], 1);    // LDS atomic
        csr_src[slot] = (int)(p & 0x1FFFFu);
    }
}

// ---------------- aggregation (bf16 rows, fp32 accumulate, 16 outstanding) ----------------
// R11 version restored (proven 63.4 us / 38% VALU). R12 lesson: the dwordx4
// 16-lane variant lands at the same duration with 62% VALU -> the gather is at
// the random-256B-row memory-path wall, not issue/MLP-bound. Do not re-tune.
__global__ __launch_bounds__(256) void gather_bf16(const ushort* __restrict__ xb,
                                                   const int* __restrict__ offsets,
                                                   const int* __restrict__ csr_src,
                                                   ushort* __restrict__ hb) {
    int wv = threadIdx.x >> 6, lane = threadIdx.x & 63;
    int node = blockIdx.x * 4 + wv;           // 25000*4 == N_NODES
    const unsigned int* base = (const unsigned int*)xb;
    unsigned int u = base[(size_t)node * 64 + lane];
    float ax = bflo(u), ay = bfhi(u);
    int b = offsets[node], e = offsets[node + 1];
    int i = b;
    for (; i + 15 < e; i += 16) {             // 16 outstanding row loads
        int s0 = csr_src[i],      s1 = csr_src[i + 1],  s2 = csr_src[i + 2],  s3 = csr_src[i + 3];
        int s4 = csr_src[i + 4],  s5 = csr_src[i + 5],  s6 = csr_src[i + 6],  s7 = csr_src[i + 7];
        int s8 = csr_src[i + 8],  s9 = csr_src[i + 9],  sa = csr_src[i + 10], sb = csr_src[i + 11];
        int sc = csr_src[i + 12], sd = csr_src[i + 13], se = csr_src[i + 14], sf = csr_src[i + 15];
        unsigned int v0 = base[(size_t)s0 * 64 + lane];
        unsigned int v1 = base[(size_t)s1 * 64 + lane];
        unsigned int v2 = base[(size_t)s2 * 64 + lane];
        unsigned int v3 = base[(size_t)s3 * 64 + lane];
        unsigned int v4 = base[(size_t)s4 * 64 + lane];
        unsigned int v5 = base[(size_t)s5 * 64 + lane];
        unsigned int v6 = base[(size_t)s6 * 64 + lane];
        unsigned int v7 = base[(size_t)s7 * 64 + lane];
        unsigned int v8 = base[(size_t)s8 * 64 + lane];
        unsigned int v9 = base[(size_t)s9 * 64 + lane];
        unsigned int va = base[(size_t)sa * 64 + lane];
        unsigned int vb = base[(size_t)sb * 64 + lane];
        unsigned int vc = base[(size_t)sc * 64 + lane];
        unsigned int vd = base[(size_t)sd * 64 + lane];
        unsigned int ve = base[(size_t)se * 64 + lane];
        unsigned int vf = base[(size_t)sf * 64 + lane];
        ax += bflo(v0) + bflo(v1) + bflo(v2) + bflo(v3)
            + bflo(v4) + bflo(v5) + bflo(v6) + bflo(v7)
            + bflo(v8) + bflo(v9) + bflo(va) + bflo(vb)
            + bflo(vc) + bflo(vd) + bflo(ve) + bflo(vf);
        ay += bfhi(v0) + bfhi(v1) + bfhi(v2) + bfhi(v3)
            + bfhi(v4) + bfhi(v5) + bfhi(v6) + bfhi(v7)
            + bfhi(v8) + bfhi(v9) + bfhi(va) + bfhi(vb)
            + bfhi(vc) + bfhi(vd) + bfhi(ve) + bfhi(vf);
    }
    for (; i + 3 < e; i += 4) {
        int s0 = csr_src[i], s1 = csr_src[i + 1], s2 = csr_src[i + 2], s3 = csr_src[i + 3];
        unsigned int v0 = base[(size_t)s0 * 64 + lane];
        unsigned int v1 = base[(size_t)s1 * 64 + lane];
        unsigned int v2 = base[(size_t)s2 * 64 + lane];
        unsigned int v3 = base[(size_t)s3 * 64 + lane];
        ax += bflo(v0) + bflo(v1) + bflo(v2) + bflo(v3);
        ay += bfhi(v0) + bfhi(v1) + bfhi(v2) + bfhi(v3);
    }
    for (; i < e; ++i) {
        unsigned int v = base[(size_t)csr_src[i] * 64 + lane];
        ax += bflo(v); ay += bfhi(v);
    }
    ((unsigned int*)hb)[(size_t)node * 64 + lane] = packbf(ax, ay);
}

// ---------------- fused layer: out = relu(relu(BN(in@W1))@W2 + b2) ----------------
// R9 structure + W2 register prefetch: the 4x16B W2 loads are issued BEFORE
// the gemm1 MFMA loop (independent -> overlap 32 MFMAs + H writes), so the
// restage between the two barriers is just regs->LDS stores, removing the
// exposed global-read latency from every block's inter-gemm critical path.
__global__ __launch_bounds__(512, 4) void fused_gemm(const ushort* __restrict__ in,
                                                     ushort* __restrict__ out,
                                                     const ushort* __restrict__ Wt1,
                                                     const ushort* __restrict__ Wt2,
                                                     const float* __restrict__ fold1,
                                                     const float* __restrict__ fold2) {
    __shared__ ushort As[128 * 136];    // A tile -> H tile -> C tile (aliased)
    __shared__ ushort Bs[128 * 136];    // W1^T, then W2^T
    int t = threadIdx.x;
    int row0 = blockIdx.x * 128;        // 782 blocks, last partial (32 rows)

#pragma unroll
    for (int i = 0; i < 4; ++i) {       // stage A + W1
        int f = t + 512 * i; int m = f >> 4, g = f & 15;
        *(float4*)(As + m * 136 + g * 8) = *(const float4*)(in + (size_t)(row0 + m) * D + g * 8);
        *(float4*)(Bs + m * 136 + g * 8) = *(const float4*)(Wt1 + (size_t)m * D + g * 8);
    }
    // W2 prefetch into registers (consumed at restage, after gemm1)
    const uint4* w2v = (const uint4*)Wt2;
    uint4 p0 = w2v[t];
    uint4 p1 = w2v[t + 512];
    uint4 p2 = w2v[t + 1024];
    uint4 p3 = w2v[t + 1536];
    __syncthreads();

    int lane = t & 63, wv = t >> 6;
    int quad = lane >> 4, mr = lane & 15;
    int mbase = wv * 16;
    const ushort* ap = As + (mbase + mr) * 136 + quad * 8;
    bf16x8 a0 = *(const bf16x8*)(ap);
    bf16x8 a1 = *(const bf16x8*)(ap + 32);
    bf16x8 a2 = *(const bf16x8*)(ap + 64);
    bf16x8 a3 = *(const bf16x8*)(ap + 96);

    // --- GEMM1: H = relu(BN(A@W1)) -> As own rows (in-wave DS ordering: safe)
#pragma unroll
    for (int nt = 0; nt < 8; ++nt) {
        const ushort* bq = Bs + (nt * 16 + mr) * 136 + quad * 8;
        bf16x8 b0 = *(const bf16x8*)(bq);
        bf16x8 b1 = *(const bf16x8*)(bq + 32);
        bf16x8 b2 = *(const bf16x8*)(bq + 64);
        bf16x8 b3 = *(const bf16x8*)(bq + 96);
        f32x4 acc = {0.f, 0.f, 0.f, 0.f};
        acc = __builtin_amdgcn_mfma_f32_16x16x32_bf16(a0, b0, acc, 0, 0, 0);
        acc = __builtin_amdgcn_mfma_f32_16x16x32_bf16(a1, b1, acc, 0, 0, 0);
        acc = __builtin_amdgcn_mfma_f32_16x16x32_bf16(a2, b2, acc, 0, 0, 0);
        acc = __builtin_amdgcn_mfma_f32_16x16x32_bf16(a3, b3, acc, 0, 0, 0);
        int j = nt * 16 + mr;           // C/D: col=lane&15, row=quad*4+reg (m89)
        float s = fold1[j], o = fold1[D + j];
#pragma unroll
        for (int r = 0; r < 4; ++r) {
            float z = fmaxf(fmaf(acc[r], s, o), 0.0f);
            As[(mbase + quad * 4 + r) * 136 + j] = f2bf(z);
        }
    }
    __syncthreads();                    // all waves done reading W1 from Bs

    {                                   // restage Bs with prefetched W2 (regs->LDS)
        int f0 = t;          *(uint4*)(Bs + (f0 >> 4) * 136 + (f0 & 15) * 8) = p0;
        int f1 = t + 512;    *(uint4*)(Bs + (f1 >> 4) * 136 + (f1 & 15) * 8) = p1;
        int f2 = t + 1024;   *(uint4*)(Bs + (f2 >> 4) * 136 + (f2 & 15) * 8) = p2;
        int f3 = t + 1536;   *(uint4*)(Bs + (f3 >> 4) * 136 + (f3 & 15) * 8) = p3;
    }
    const ushort* hp = As + (mbase + mr) * 136 + quad * 8;
    bf16x8 h0 = *(const bf16x8*)(hp);
    bf16x8 h1 = *(const bf16x8*)(hp + 32);
    bf16x8 h2 = *(const bf16x8*)(hp + 64);
    bf16x8 h3 = *(const bf16x8*)(hp + 96);
    __syncthreads();                    // W2 staged

    // --- GEMM2: C = relu(H@W2 + b2) -> As own rows
#pragma unroll
    for (int nt = 0; nt < 8; ++nt) {
        const ushort* bq = Bs + (nt * 16 + mr) * 136 + quad * 8;
        bf16x8 b0 = *(const bf16x8*)(bq);
        bf16x8 b1 = *(const bf16x8*)(bq + 32);
        bf16x8 b2 = *(const bf16x8*)(bq + 64);
        bf16x8 b3 = *(const bf16x8*)(bq + 96);
        f32x4 acc = {0.f, 0.f, 0.f, 0.f};
        acc = __builtin_amdgcn_mfma_f32_16x16x32_bf16(h0, b0, acc, 0, 0, 0);
        acc = __builtin_amdgcn_mfma_f32_16x16x32_bf16(h1, b1, acc, 0, 0, 0);
        acc = __builtin_amdgcn_mfma_f32_16x16x32_bf16(h2, b2, acc, 0, 0, 0);
        acc = __builtin_amdgcn_mfma_f32_16x16x32_bf16(h3, b3, acc, 0, 0, 0);
        int j = nt * 16 + mr;
        float o = fold2[D + j];
#pragma unroll
        for (int r = 0; r < 4; ++r) {
            float z = fmaxf(acc[r] + o, 0.0f);
            As[(mbase + quad * 4 + r) * 136 + j] = f2bf(z);
        }
    }
    __syncthreads();

#pragma unroll
    for (int i = 0; i < 8; ++i) {       // coalesced copy-out, float2 = 4 bf16
        int f = t + 512 * i; int lr = f >> 5, g = f & 31;
        if (row0 + lr < N_NODES)
            *(float2*)(out + (size_t)(row0 + lr) * D + g * 4) =
                *(const float2*)(As + lr * 136 + g * 4);
    }
}

// ---------------- pooling + head fused: out[r] = relu(pool(r)@W1+b1)@W2+b2 ----------------
__global__ __launch_bounds__(128) void poolhead_kernel(const ushort* __restrict__ xb,
                                                       const int* __restrict__ gstart,
                                                       const float* __restrict__ W1,
                                                       const float* __restrict__ b1,
                                                       const float* __restrict__ W2,
                                                       const float* __restrict__ b2,
                                                       float* __restrict__ out) {
    __shared__ float row[128];
    __shared__ float t1[128];
    int r = blockIdx.x, j = threadIdx.x;
    float acc = 0.0f;
    int b = gstart[r], e = gstart[r + 1];
    for (int i = b; i < e; ++i)
        acc += __uint_as_float(((unsigned int)xb[(size_t)i * D + j]) << 16);
    row[j] = acc;
    __syncthreads();
    float a1 = b1[j];
    for (int k = 0; k < D; ++k) a1 = fmaf(row[k], W1[k * D + j], a1);
    t1[j] = fmaxf(a1, 0.0f);
    __syncthreads();
    float a2 = b2[j];
    for (int k = 0; k < D; ++k) a2 = fmaf(t1[k], W2[k * D + j], a2);
    out[r * D + j] = a2;
}

// ---------------- launcher ----------------
extern "C" void kernel_launch(void* const* d_in, const int* in_sizes, int n_in,
                              void* d_out, int out_size, void* d_ws, size_t ws_size,
                              hipStream_t stream) {
    const float* x        = (const float*)d_in[0];
    const int*   ei       = (const int*)d_in[1];
    const int*   src      = ei;
    const int*   dst      = ei + N_EDGES;
    const int*   batch    = (const int*)d_in[2];
    const float* conv_W1  = (const float*)d_in[3];
    const float* conv_b1  = (const float*)d_in[4];
    const float* bn_gamma = (const float*)d_in[5];
    const float* bn_beta  = (const float*)d_in[6];
    const float* bn_mean  = (const float*)d_in[7];
    const float* bn_var   = (const float*)d_in[8];
    const float* conv_W2  = (const float*)d_in[9];
    const float* conv_b2  = (const float*)d_in[10];
    const float* head_W1  = (const float*)d_in[11];
    const float* head_b1  = (const float*)d_in[12];
    const float* head_W2  = (const float*)d_in[13];
    const float* head_b2  = (const float*)d_in[14];
    float* out = (float*)d_out;

    char* ws = (char*)d_ws;
    size_t off = 0;
    auto alloc = [&](size_t bytes) -> void* {
        void* p = ws + off;
        off = (off + bytes + 255) & ~(size_t)255;
        return p;
    };
    const size_t NODE_BUF = (size_t)(N_NODES + 128) * D * sizeof(ushort);
    ushort* buf0    = (ushort*)alloc(NODE_BUF);
    ushort* buf1    = (ushort*)alloc(NODE_BUF);
    ushort* Wt      = (ushort*)alloc((size_t)6 * D * D * sizeof(ushort));
    float*  folds   = (float*)alloc((size_t)6 * 2 * D * sizeof(float));
    unsigned int* squeue = (unsigned int*)alloc((size_t)FNSLICE * FSLICE_CAP * sizeof(unsigned int));
    int*   csr_src  = (int*)alloc((size_t)(N_EDGES + 64) * sizeof(int));
    int*   offsets  = (int*)alloc((size_t)(N_NODES + 1) * sizeof(int));
    int*   slice_tail = (int*)alloc((size_t)FNSLICE * sizeof(int));
    int*   gstart   = (int*)alloc((size_t)(N_GRAPHS + 1) * sizeof(int));

    setup_kernel<<<SETUP_GRID, 256, 0, stream>>>(
        x, buf0, conv_W1, conv_W2, Wt,
        conv_b1, bn_gamma, bn_beta, bn_mean, bn_var, conv_b2, folds,
        batch, gstart, slice_tail, offsets);
    compact_kernel<<<CGRID, 256, 0, stream>>>(src, dst, squeue, slice_tail);
    fill_local<<<FNSLICE, 1024, 0, stream>>>(squeue, slice_tail, offsets, csr_src);

    const int FUSED_GRID = (N_NODES + 127) / 128;   // 782
    for (int l = 0; l < 3; ++l) {
        gather_bf16<<<N_NODES / 4, 256, 0, stream>>>(buf0, offsets, csr_src, buf1);
        fused_gemm<<<FUSED_GRID, 512, 0, stream>>>(buf1, buf0,
            Wt + (size_t)(2 * l) * D * D, Wt + (size_t)(2 * l + 1) * D * D,
            folds + (size_t)(2 * l) * 2 * D, folds + (size_t)(2 * l + 1) * 2 * D);
    }

    poolhead_kernel<<<N_GRAPHS, 128, 0, stream>>>(buf0, gstart, head_W1, head_b1,
                                                  head_W2, head_b2, out);
}